// Round 8
// baseline (290.681 us; speedup 1.0000x reference)
//
#include <hip/hip_runtime.h>
#include <hip/hip_bf16.h>

#define CH 128          // HID_CH == OUT_CH == 128
#define IN_CH_K 512
#define CHUNK 2048      // edges per bucket-sort block (782 blocks -> ~3/CU)
#define BPAD 5120       // padded per-bucket capacity (expect ~4096, 16-sigma margin)

typedef short s16x8 __attribute__((ext_vector_type(8)));   // 8 bf16 (4 VGPRs)
typedef float f32x4 __attribute__((ext_vector_type(4)));

__device__ __forceinline__ unsigned int f2bf(float f) {
    unsigned int u = __builtin_bit_cast(unsigned int, f);
    return (u + 0x7fffu + ((u >> 16) & 1u)) >> 16;
}
// packed f32x2 -> bf16x2 via HW cvt (RNE, same bits as f2bf)
__device__ __forceinline__ unsigned int pk2bf(float lo, float hi) {
    unsigned int r;
    asm("v_cvt_pk_bf16_f32 %0, %1, %2" : "=v"(r) : "v"(lo), "v"(hi));
    return r;
}
__device__ __forceinline__ float bf_lo(unsigned int u) {
    return __builtin_bit_cast(float, u << 16);
}
__device__ __forceinline__ float bf_hi(unsigned int u) {
    return __builtin_bit_cast(float, u & 0xFFFF0000u);
}
// relu on 2 packed bf16: zero each 16-bit half whose sign bit is set
__device__ __forceinline__ unsigned int relu_pk(unsigned int w) {
    unsigned int keep = (~w) & 0x80008000u;
    unsigned int mask = keep - (keep >> 15);
    return w & mask;
}

// ---------------- bucket-sort CSR build ----------------
__global__ void init_cursor_kernel(int* __restrict__ cursor, int NB) {
    int i = blockIdx.x * blockDim.x + threadIdx.x;
    if (i < NB) cursor[i] = i * BPAD;
}

// bin edges into padded bucket regions; per-edge cursors in LDS, one global atomic per (block,bucket)
__global__ void bin_kernel(const int* __restrict__ src, const int* __restrict__ dst,
                           int* __restrict__ cursor, int* __restrict__ binned,
                           int E, int NB) {
    __shared__ int h[512];
    __shared__ int base[512];
    __shared__ int cur[512];
    const int tid = threadIdx.x;
    for (int i = tid; i < NB; i += 256) h[i] = 0;
    __syncthreads();

    const int E4 = E >> 2;
    const int beg4 = blockIdx.x * (CHUNK / 4);
    const int end4 = min(E4, beg4 + CHUNK / 4);
    const int4* dst4 = reinterpret_cast<const int4*>(dst);
    const int4* src4 = reinterpret_cast<const int4*>(src);
    const bool last = (blockIdx.x == gridDim.x - 1);

    for (int e4 = beg4 + tid; e4 < end4; e4 += 256) {
        int4 d = dst4[e4];
        atomicAdd(&h[d.x >> 8], 1);
        atomicAdd(&h[d.y >> 8], 1);
        atomicAdd(&h[d.z >> 8], 1);
        atomicAdd(&h[d.w >> 8], 1);
    }
    if (last) {
        for (int e = (E & ~3) + tid; e < E; e += 256)
            atomicAdd(&h[dst[e] >> 8], 1);
    }
    __syncthreads();
    for (int i = tid; i < NB; i += 256) {
        cur[i] = 0;
        if (h[i]) base[i] = atomicAdd(&cursor[i], h[i]);
    }
    __syncthreads();

    for (int e4 = beg4 + tid; e4 < end4; e4 += 256) {
        int4 d = dst4[e4];
        int4 s = src4[e4];
        int b, r, idx;
        b = d.x >> 8; r = atomicAdd(&cur[b], 1); idx = base[b] + r;
        if (idx < (b + 1) * BPAD) binned[idx] = s.x | ((d.x & 255) << 17);
        b = d.y >> 8; r = atomicAdd(&cur[b], 1); idx = base[b] + r;
        if (idx < (b + 1) * BPAD) binned[idx] = s.y | ((d.y & 255) << 17);
        b = d.z >> 8; r = atomicAdd(&cur[b], 1); idx = base[b] + r;
        if (idx < (b + 1) * BPAD) binned[idx] = s.z | ((d.z & 255) << 17);
        b = d.w >> 8; r = atomicAdd(&cur[b], 1); idx = base[b] + r;
        if (idx < (b + 1) * BPAD) binned[idx] = s.w | ((d.w & 255) << 17);
    }
    if (last) {
        for (int e = (E & ~3) + tid; e < E; e += 256) {
            int d = dst[e];
            int b = d >> 8;
            int r = atomicAdd(&cur[b], 1);
            int idx = base[b] + r;
            if (idx < (b + 1) * BPAD) binned[idx] = src[e] | ((d & 255) << 17);
        }
    }
}

// per-bucket (256 nodes) CSR finalize: row ranges, dinv, csr_src; per-edge atomics in LDS
__global__ void csr_bucket_kernel(const int* __restrict__ binned, const int* __restrict__ cursor,
                                  int2* __restrict__ row_range, int* __restrict__ csr_src,
                                  float* __restrict__ dinv, int N) {
    __shared__ int cnt[256];
    __shared__ int off[256];
    __shared__ int cur[256];
    const int k = blockIdx.x;
    const int t = threadIdx.x;
    cnt[t] = 0;
    __syncthreads();
    const int beg = k * BPAD;
    const int end = min(cursor[k], (k + 1) * BPAD);
    const int nv = (end - beg) & ~3;        // vectorizable count (beg is 16B-aligned)
    const int4* b4 = reinterpret_cast<const int4*>(binned + beg);

    for (int q = t; q * 4 < nv; q += 256) {
        int4 p = b4[q];
        atomicAdd(&cnt[p.x >> 17], 1);
        atomicAdd(&cnt[p.y >> 17], 1);
        atomicAdd(&cnt[p.z >> 17], 1);
        atomicAdd(&cnt[p.w >> 17], 1);
    }
    for (int e = beg + nv + t; e < end; e += 256)
        atomicAdd(&cnt[binned[e] >> 17], 1);
    __syncthreads();
    int v = cnt[t];
    off[t] = v;
    __syncthreads();
    #pragma unroll
    for (int o = 1; o < 256; o <<= 1) {
        int tv = (t >= o) ? off[t - o] : 0;
        __syncthreads();
        off[t] += tv;
        __syncthreads();
    }
    int ex = off[t] - v;
    int node = k * 256 + t;
    if (node < N) {
        row_range[node] = make_int2(beg + ex, beg + ex + v);
        dinv[node] = rsqrtf((float)(v + 1));   // +1 self-loop
    }
    cur[t] = ex;
    __syncthreads();
    for (int q = t; q * 4 < nv; q += 256) {
        int4 p = b4[q];
        int dl, r;
        dl = p.x >> 17; r = atomicAdd(&cur[dl], 1); csr_src[beg + r] = p.x & 0x1FFFF;
        dl = p.y >> 17; r = atomicAdd(&cur[dl], 1); csr_src[beg + r] = p.y & 0x1FFFF;
        dl = p.z >> 17; r = atomicAdd(&cur[dl], 1); csr_src[beg + r] = p.z & 0x1FFFF;
        dl = p.w >> 17; r = atomicAdd(&cur[dl], 1); csr_src[beg + r] = p.w & 0x1FFFF;
    }
    for (int e = beg + nv + t; e < end; e += 256) {
        int p = binned[e];
        int dl = p >> 17;
        int r = atomicAdd(&cur[dl], 1);
        csr_src[beg + r] = p & 0x1FFFF;
    }
}

// ---------------- weight pre-transpose to MFMA B-fragment layout ----------------
// WT[g*128 + col] (uint4 = 8 bf16) holds W[k(g*8+j)][col], j=0..7.
// PERM: storage k' -> true k = (k'>>3) + ((k'&7)<<4)  (layer 2: A cols are permuted)
template<bool PERM>
__global__ void convert_w_kernel(const float* __restrict__ W, uint4* __restrict__ WT, int K) {
    int i = blockIdx.x * blockDim.x + threadIdx.x;
    int ng = K >> 3;
    if (i >= ng * CH) return;
    int g = i >> 7;
    int col = i & 127;
    unsigned int h[8];
    #pragma unroll
    for (int j = 0; j < 8; ++j) {
        int kp = g * 8 + j;
        int k = PERM ? ((kp >> 3) + ((kp & 7) << 4)) : kp;
        h[j] = f2bf(W[(size_t)k * CH + col]);
    }
    uint4 v;
    v.x = h[0] | (h[1] << 16);
    v.y = h[2] | (h[3] << 16);
    v.z = h[4] | (h[5] << 16);
    v.w = h[6] | (h[7] << 16);
    WT[i] = v;
}

// ---------------- GEMM1: g1[M][128](bf16, permuted cols) = (x[M][512] @ W1) * dinv[row] ----------------
// Max memory-level parallelism: each wave owns 16 rows x 128 cols and issues ALL 32 A-loads
// (16 rows x 2KB = 32KB in flight per wave) before the K-loop; consumes them in issue order
// (compiler inserts descending vmcnt waits). B (L2-resident) prefetched 1-deep.
// storage col' = l15*8 + n  (true col = n*16 + l15)
__launch_bounds__(256, 2)
__global__ void gemm1_mfma_kernel(const float* __restrict__ A, const uint4* __restrict__ WT,
                                  const float* __restrict__ dinv, unsigned short* __restrict__ C,
                                  int M) {
    const int tid = threadIdx.x;
    const int wid = tid >> 6;
    const int lane = tid & 63;
    const int l15 = lane & 15;
    const int lg = lane >> 4;

    const int wave_row = blockIdx.x * 64 + wid * 16;   // 16 rows per wave
    const int arow = min(wave_row + l15, M - 1);
    // lane's A slice base: row arow, float4 index lg*2 (+ ks*8 per k-step)
    const float4* ap = reinterpret_cast<const float4*>(A + (size_t)arow * IN_CH_K) + lg * 2;

    // ---- issue the wave's entire A footprint (32 loads, 32 KB) ----
    float4 a[16][2];
    #pragma unroll
    for (int ks = 0; ks < 16; ++ks) {
        a[ks][0] = ap[ks * 8];
        a[ks][1] = ap[ks * 8 + 1];
    }

    // ---- B prologue (k-step 0) ----
    const uint4* wp = WT + (size_t)lg * CH + l15;   // +4*CH per k-step; +16*n per frag
    uint4 bw[8];
    #pragma unroll
    for (int n = 0; n < 8; ++n) bw[n] = wp[n * 16];

    f32x4 acc[8];
    #pragma unroll
    for (int n = 0; n < 8; ++n) acc[n] = (f32x4){0.f, 0.f, 0.f, 0.f};

    #pragma unroll
    for (int ks = 0; ks < 16; ++ks) {
        // prefetch next k-step's B fragments (L2-resident, short latency)
        uint4 nbw[8];
        if (ks < 15) {
            const uint4* nwp = wp + (size_t)(ks + 1) * 4 * CH;
            #pragma unroll
            for (int n = 0; n < 8; ++n) nbw[n] = nwp[n * 16];
        }

        // convert this k-step's A (already in flight / landed) to bf16
        uint4 pk;
        pk.x = pk2bf(a[ks][0].x, a[ks][0].y);
        pk.y = pk2bf(a[ks][0].z, a[ks][0].w);
        pk.z = pk2bf(a[ks][1].x, a[ks][1].y);
        pk.w = pk2bf(a[ks][1].z, a[ks][1].w);
        s16x8 af = __builtin_bit_cast(s16x8, pk);

        #pragma unroll
        for (int n = 0; n < 8; ++n) {
            s16x8 b = __builtin_bit_cast(s16x8, bw[n]);
            acc[n] = __builtin_amdgcn_mfma_f32_16x16x32_bf16(af, b, acc[n], 0, 0, 0);
        }

        if (ks < 15) {
            #pragma unroll
            for (int n = 0; n < 8; ++n) bw[n] = nbw[n];
        }
    }

    // ---- epilogue: D[row=lg*4+i][col=l15] per frag; scale by dinv[row]; permuted bf16 store ----
    #pragma unroll
    for (int i = 0; i < 4; ++i) {
        int row = wave_row + lg * 4 + i;
        if (row < M) {
            float s = dinv[row];
            uint4 v;
            v.x = pk2bf(acc[0][i] * s, acc[1][i] * s);
            v.y = pk2bf(acc[2][i] * s, acc[3][i] * s);
            v.z = pk2bf(acc[4][i] * s, acc[5][i] * s);
            v.w = pk2bf(acc[6][i] * s, acc[7][i] * s);
            *reinterpret_cast<uint4*>(&C[(size_t)row * CH + l15 * 8]) = v;
        }
    }
}

// ---------------- GEMM2: g2 = (relu(a1)[M][128] @ W2) * dinv[row], all bf16 permuted ----------------
__launch_bounds__(256)
__global__ void gemm2_mfma_kernel(const unsigned short* __restrict__ A, const uint4* __restrict__ WT,
                                  const float* __restrict__ dinv, unsigned short* __restrict__ C,
                                  int M) {
    const int tid = threadIdx.x;
    const int wid = tid >> 6;
    const int lane = tid & 63;
    const int l15 = lane & 15;
    const int lg = lane >> 4;

    const int block_row = blockIdx.x * 128 + wid * 32;

    f32x4 acc[2][8];
    #pragma unroll
    for (int m = 0; m < 2; ++m)
        #pragma unroll
        for (int n = 0; n < 8; ++n)
            acc[m][n] = (f32x4){0.f, 0.f, 0.f, 0.f};

    int arow0 = min(block_row + l15, M - 1);
    int arow1 = min(block_row + 16 + l15, M - 1);
    const uint4* ap0 = reinterpret_cast<const uint4*>(A + (size_t)arow0 * CH);
    const uint4* ap1 = reinterpret_cast<const uint4*>(A + (size_t)arow1 * CH);

    #pragma unroll
    for (int k0 = 0; k0 < CH; k0 += 32) {
        const int fi = (k0 >> 3) + lg;
        uint4 r0 = ap0[fi];
        uint4 r1 = ap1[fi];
        r0.x = relu_pk(r0.x); r0.y = relu_pk(r0.y); r0.z = relu_pk(r0.z); r0.w = relu_pk(r0.w);
        r1.x = relu_pk(r1.x); r1.y = relu_pk(r1.y); r1.z = relu_pk(r1.z); r1.w = relu_pk(r1.w);
        s16x8 a0 = __builtin_bit_cast(s16x8, r0);
        s16x8 a1 = __builtin_bit_cast(s16x8, r1);
        #pragma unroll
        for (int n = 0; n < 8; ++n) {
            uint4 bv = WT[(size_t)fi * CH + n * 16 + l15];
            s16x8 b = __builtin_bit_cast(s16x8, bv);
            acc[0][n] = __builtin_amdgcn_mfma_f32_16x16x32_bf16(a0, b, acc[0][n], 0, 0, 0);
            acc[1][n] = __builtin_amdgcn_mfma_f32_16x16x32_bf16(a1, b, acc[1][n], 0, 0, 0);
        }
    }

    #pragma unroll
    for (int m = 0; m < 2; ++m) {
        #pragma unroll
        for (int i = 0; i < 4; ++i) {
            int row = block_row + m * 16 + lg * 4 + i;
            if (row < M) {
                float s = dinv[row];
                uint4 v;
                v.x = pk2bf(acc[m][0][i] * s, acc[m][1][i] * s);
                v.y = pk2bf(acc[m][2][i] * s, acc[m][3][i] * s);
                v.z = pk2bf(acc[m][4][i] * s, acc[m][5][i] * s);
                v.w = pk2bf(acc[m][6][i] * s, acc[m][7][i] * s);
                *reinterpret_cast<uint4*>(&C[(size_t)row * CH + l15 * 8]) = v;
            }
        }
    }
}

// ---------------- aggregation: out[d] = dinv[d]*(g[d] + sum g[src]) + bias ----------------
// g is bf16 permuted-col [node][128]; one wave per node, 1 uint (2 bf16) per lane.
// 8-deep software-pipelined gather: next batch's indices load while current gathers fly.
#define GATHER(cc) g[(size_t)__builtin_amdgcn_readfirstlane(cc) * 64 + lane]
template<bool OUT_BF16>
__launch_bounds__(256)
__global__ void aggregate_kernel(const unsigned int* __restrict__ g, const int2* __restrict__ row_range,
                                 const int* __restrict__ csr_src, const float* __restrict__ dinv,
                                 const float* __restrict__ bias, void* __restrict__ outp, int N) {
    const int gtid = blockIdx.x * blockDim.x + threadIdx.x;
    const int node = gtid >> 6;
    if (node >= N) return;
    const int lane = threadIdx.x & 63;

    unsigned int su = g[(size_t)node * 64 + lane];   // self-loop term
    const int2 rr = row_range[node];
    float ax = bf_lo(su);
    float ay = bf_hi(su);

    int j = rr.x;
    const int end = rr.y;

    if (j + 8 <= end) {
        int c0 = csr_src[j], c1 = csr_src[j+1], c2 = csr_src[j+2], c3 = csr_src[j+3];
        int c4 = csr_src[j+4], c5 = csr_src[j+5], c6 = csr_src[j+6], c7 = csr_src[j+7];
        j += 8;
        while (j + 8 <= end) {
            int n0 = csr_src[j], n1 = csr_src[j+1], n2 = csr_src[j+2], n3 = csr_src[j+3];
            int n4 = csr_src[j+4], n5 = csr_src[j+5], n6 = csr_src[j+6], n7 = csr_src[j+7];
            j += 8;
            unsigned int u0 = GATHER(c0), u1 = GATHER(c1), u2 = GATHER(c2), u3 = GATHER(c3);
            unsigned int u4 = GATHER(c4), u5 = GATHER(c5), u6 = GATHER(c6), u7 = GATHER(c7);
            ax += ((bf_lo(u0) + bf_lo(u1)) + (bf_lo(u2) + bf_lo(u3)))
                + ((bf_lo(u4) + bf_lo(u5)) + (bf_lo(u6) + bf_lo(u7)));
            ay += ((bf_hi(u0) + bf_hi(u1)) + (bf_hi(u2) + bf_hi(u3)))
                + ((bf_hi(u4) + bf_hi(u5)) + (bf_hi(u6) + bf_hi(u7)));
            c0 = n0; c1 = n1; c2 = n2; c3 = n3;
            c4 = n4; c5 = n5; c6 = n6; c7 = n7;
        }
        unsigned int u0 = GATHER(c0), u1 = GATHER(c1), u2 = GATHER(c2), u3 = GATHER(c3);
        unsigned int u4 = GATHER(c4), u5 = GATHER(c5), u6 = GATHER(c6), u7 = GATHER(c7);
        ax += ((bf_lo(u0) + bf_lo(u1)) + (bf_lo(u2) + bf_lo(u3)))
            + ((bf_lo(u4) + bf_lo(u5)) + (bf_lo(u6) + bf_lo(u7)));
        ay += ((bf_hi(u0) + bf_hi(u1)) + (bf_hi(u2) + bf_hi(u3)))
            + ((bf_hi(u4) + bf_hi(u5)) + (bf_hi(u6) + bf_hi(u7)));
    }
    for (; j + 2 <= end; j += 2) {
        int c0 = csr_src[j], c1 = csr_src[j+1];
        unsigned int u0 = GATHER(c0), u1 = GATHER(c1);
        ax += bf_lo(u0) + bf_lo(u1);
        ay += bf_hi(u0) + bf_hi(u1);
    }
    if (j < end) {
        int c0 = csr_src[j];
        unsigned int u0 = GATHER(c0);
        ax += bf_lo(u0);
        ay += bf_hi(u0);
    }

    const int cp0 = lane << 1;
    const int cp1 = cp0 | 1;
    const int c0 = (cp0 >> 3) + ((cp0 & 7) << 4);    // true cols
    const int c1 = (cp1 >> 3) + ((cp1 & 7) << 4);
    const float di = dinv[node];
    float ox = di * ax + bias[c0];
    float oy = di * ay + bias[c1];
    if (OUT_BF16) {
        ((unsigned int*)outp)[(size_t)node * 64 + lane] = pk2bf(ox, oy);
    } else {
        float* o = (float*)outp + (size_t)node * CH;
        o[c0] = ox;
        o[c1] = oy;
    }
}

extern "C" void kernel_launch(void* const* d_in, const int* in_sizes, int n_in,
                              void* d_out, int out_size, void* d_ws, size_t ws_size,
                              hipStream_t stream) {
    const float* x  = (const float*)d_in[0];
    const int*   ei = (const int*)d_in[1];
    const float* W1 = (const float*)d_in[2];
    const float* b1 = (const float*)d_in[3];
    const float* W2 = (const float*)d_in[4];
    const float* b2 = (const float*)d_in[5];
    float* out = (float*)d_out;

    const int N = in_sizes[0] / IN_CH_K;       // 100000
    const int E = in_sizes[1] / 2;             // 1600000
    const int* e_src = ei;
    const int* e_dst = ei + E;

    const int NB = (N + 255) >> 8;             // 391 coarse buckets
    const int NCHUNK = (E + CHUNK - 1) / CHUNK;

    char* w = (char*)d_ws;
    auto alloc = [&](size_t bytes) {
        char* p = w;
        w += (bytes + 255) & ~(size_t)255;
        return p;
    };
    int*   cursor    = (int*)  alloc((size_t)NB * 4);
    int2*  row_range = (int2*) alloc((size_t)N * 8);
    float* dinv      = (float*)alloc((size_t)N * 4);
    int*   csr_src   = (int*)  alloc((size_t)NB * BPAD * 4);
    uint4* w1t       = (uint4*)alloc((size_t)(IN_CH_K / 8) * CH * 16);
    uint4* w2t       = (uint4*)alloc((size_t)(CH / 8) * CH * 16);
    unsigned short* gbuf = (unsigned short*)alloc((size_t)N * CH * 2);  // g1 / g2
    unsigned short* abuf = (unsigned short*)alloc((size_t)N * CH * 2);  // a1
    int* binned = (int*)gbuf;   // aliases gbuf (8 MB < 25.6 MB): dead before gemm1 writes

    // ---- CSR build (padded bucket sort) + weight conversion ----
    init_cursor_kernel<<<(NB + 255) / 256, 256, 0, stream>>>(cursor, NB);
    bin_kernel<<<NCHUNK, 256, 0, stream>>>(e_src, e_dst, cursor, binned, E, NB);
    csr_bucket_kernel<<<NB, 256, 0, stream>>>(binned, cursor, row_range, csr_src, dinv, N);
    convert_w_kernel<false><<<(IN_CH_K / 8 * CH + 255) / 256, 256, 0, stream>>>(W1, w1t, IN_CH_K);
    convert_w_kernel<true><<<(CH / 8 * CH + 255) / 256, 256, 0, stream>>>(W2, w2t, CH);

    const int gemm1_grid = (N + 63) / 64;      // 64 rows per block (4 waves x 16 rows)
    const int gemm2_grid = (N + 127) / 128;
    const int agg_grid = (N * 64 + 255) / 256;

    // ---- layer 1 ----
    gemm1_mfma_kernel<<<gemm1_grid, 256, 0, stream>>>(x, w1t, dinv, gbuf, N);
    aggregate_kernel<true><<<agg_grid, 256, 0, stream>>>((const unsigned int*)gbuf, row_range,
                                                         csr_src, dinv, b1, abuf, N);

    // ---- layer 2 ----
    gemm2_mfma_kernel<<<gemm2_grid, 256, 0, stream>>>(abuf, w2t, dinv, gbuf, N);
    aggregate_kernel<false><<<agg_grid, 256, 0, stream>>>((const unsigned int*)gbuf, row_range,
                                                          csr_src, dinv, b2, out, N);
}

// Round 9
// 286.821 us; speedup vs baseline: 1.0135x; 1.0135x over previous
//
#include <hip/hip_runtime.h>
#include <hip/hip_bf16.h>

#define CH 128          // HID_CH == OUT_CH == 128
#define IN_CH_K 512
#define CHUNK 2048      // edges per bucket-sort block (782 blocks -> ~3/CU)
#define BPAD 5120       // padded per-bucket capacity (expect ~4096, 16-sigma margin)

typedef short s16x8 __attribute__((ext_vector_type(8)));   // 8 bf16 (4 VGPRs)
typedef float f32x4 __attribute__((ext_vector_type(4)));

__device__ __forceinline__ unsigned int f2bf(float f) {
    unsigned int u = __builtin_bit_cast(unsigned int, f);
    return (u + 0x7fffu + ((u >> 16) & 1u)) >> 16;
}
// packed f32x2 -> bf16x2 via HW cvt (RNE, same bits as f2bf)
__device__ __forceinline__ unsigned int pk2bf(float lo, float hi) {
    unsigned int r;
    asm("v_cvt_pk_bf16_f32 %0, %1, %2" : "=v"(r) : "v"(lo), "v"(hi));
    return r;
}
__device__ __forceinline__ float bf_lo(unsigned int u) {
    return __builtin_bit_cast(float, u << 16);
}
__device__ __forceinline__ float bf_hi(unsigned int u) {
    return __builtin_bit_cast(float, u & 0xFFFF0000u);
}
// relu on 2 packed bf16: zero each 16-bit half whose sign bit is set
__device__ __forceinline__ unsigned int relu_pk(unsigned int w) {
    unsigned int keep = (~w) & 0x80008000u;
    unsigned int mask = keep - (keep >> 15);
    return w & mask;
}

// ---------------- bucket-sort CSR build ----------------
__global__ void init_cursor_kernel(int* __restrict__ cursor, int NB) {
    int i = blockIdx.x * blockDim.x + threadIdx.x;
    if (i < NB) cursor[i] = i * BPAD;
}

// bin edges into padded bucket regions; per-edge cursors in LDS, one global atomic per (block,bucket)
__global__ void bin_kernel(const int* __restrict__ src, const int* __restrict__ dst,
                           int* __restrict__ cursor, int* __restrict__ binned,
                           int E, int NB) {
    __shared__ int h[512];
    __shared__ int base[512];
    __shared__ int cur[512];
    const int tid = threadIdx.x;
    for (int i = tid; i < NB; i += 256) h[i] = 0;
    __syncthreads();

    const int E4 = E >> 2;
    const int beg4 = blockIdx.x * (CHUNK / 4);
    const int end4 = min(E4, beg4 + CHUNK / 4);
    const int4* dst4 = reinterpret_cast<const int4*>(dst);
    const int4* src4 = reinterpret_cast<const int4*>(src);
    const bool last = (blockIdx.x == gridDim.x - 1);

    for (int e4 = beg4 + tid; e4 < end4; e4 += 256) {
        int4 d = dst4[e4];
        atomicAdd(&h[d.x >> 8], 1);
        atomicAdd(&h[d.y >> 8], 1);
        atomicAdd(&h[d.z >> 8], 1);
        atomicAdd(&h[d.w >> 8], 1);
    }
    if (last) {
        for (int e = (E & ~3) + tid; e < E; e += 256)
            atomicAdd(&h[dst[e] >> 8], 1);
    }
    __syncthreads();
    for (int i = tid; i < NB; i += 256) {
        cur[i] = 0;
        if (h[i]) base[i] = atomicAdd(&cursor[i], h[i]);
    }
    __syncthreads();

    for (int e4 = beg4 + tid; e4 < end4; e4 += 256) {
        int4 d = dst4[e4];
        int4 s = src4[e4];
        int b, r, idx;
        b = d.x >> 8; r = atomicAdd(&cur[b], 1); idx = base[b] + r;
        if (idx < (b + 1) * BPAD) binned[idx] = s.x | ((d.x & 255) << 17);
        b = d.y >> 8; r = atomicAdd(&cur[b], 1); idx = base[b] + r;
        if (idx < (b + 1) * BPAD) binned[idx] = s.y | ((d.y & 255) << 17);
        b = d.z >> 8; r = atomicAdd(&cur[b], 1); idx = base[b] + r;
        if (idx < (b + 1) * BPAD) binned[idx] = s.z | ((d.z & 255) << 17);
        b = d.w >> 8; r = atomicAdd(&cur[b], 1); idx = base[b] + r;
        if (idx < (b + 1) * BPAD) binned[idx] = s.w | ((d.w & 255) << 17);
    }
    if (last) {
        for (int e = (E & ~3) + tid; e < E; e += 256) {
            int d = dst[e];
            int b = d >> 8;
            int r = atomicAdd(&cur[b], 1);
            int idx = base[b] + r;
            if (idx < (b + 1) * BPAD) binned[idx] = src[e] | ((d & 255) << 17);
        }
    }
}

// per-bucket (256 nodes) CSR finalize: row ranges, dinv, csr_src; per-edge atomics in LDS
__global__ void csr_bucket_kernel(const int* __restrict__ binned, const int* __restrict__ cursor,
                                  int2* __restrict__ row_range, int* __restrict__ csr_src,
                                  float* __restrict__ dinv, int N) {
    __shared__ int cnt[256];
    __shared__ int off[256];
    __shared__ int cur[256];
    const int k = blockIdx.x;
    const int t = threadIdx.x;
    cnt[t] = 0;
    __syncthreads();
    const int beg = k * BPAD;
    const int end = min(cursor[k], (k + 1) * BPAD);
    const int nv = (end - beg) & ~3;        // vectorizable count (beg is 16B-aligned)
    const int4* b4 = reinterpret_cast<const int4*>(binned + beg);

    for (int q = t; q * 4 < nv; q += 256) {
        int4 p = b4[q];
        atomicAdd(&cnt[p.x >> 17], 1);
        atomicAdd(&cnt[p.y >> 17], 1);
        atomicAdd(&cnt[p.z >> 17], 1);
        atomicAdd(&cnt[p.w >> 17], 1);
    }
    for (int e = beg + nv + t; e < end; e += 256)
        atomicAdd(&cnt[binned[e] >> 17], 1);
    __syncthreads();
    int v = cnt[t];
    off[t] = v;
    __syncthreads();
    #pragma unroll
    for (int o = 1; o < 256; o <<= 1) {
        int tv = (t >= o) ? off[t - o] : 0;
        __syncthreads();
        off[t] += tv;
        __syncthreads();
    }
    int ex = off[t] - v;
    int node = k * 256 + t;
    if (node < N) {
        row_range[node] = make_int2(beg + ex, beg + ex + v);
        dinv[node] = rsqrtf((float)(v + 1));   // +1 self-loop
    }
    cur[t] = ex;
    __syncthreads();
    for (int q = t; q * 4 < nv; q += 256) {
        int4 p = b4[q];
        int dl, r;
        dl = p.x >> 17; r = atomicAdd(&cur[dl], 1); csr_src[beg + r] = p.x & 0x1FFFF;
        dl = p.y >> 17; r = atomicAdd(&cur[dl], 1); csr_src[beg + r] = p.y & 0x1FFFF;
        dl = p.z >> 17; r = atomicAdd(&cur[dl], 1); csr_src[beg + r] = p.z & 0x1FFFF;
        dl = p.w >> 17; r = atomicAdd(&cur[dl], 1); csr_src[beg + r] = p.w & 0x1FFFF;
    }
    for (int e = beg + nv + t; e < end; e += 256) {
        int p = binned[e];
        int dl = p >> 17;
        int r = atomicAdd(&cur[dl], 1);
        csr_src[beg + r] = p & 0x1FFFF;
    }
}

// ---------------- weight pre-transpose to MFMA B-fragment layout ----------------
// WT[g*128 + col] (uint4 = 8 bf16) holds W[k(g*8+j)][col], j=0..7.
// PERM: storage k' -> true k = (k'>>3) + ((k'&7)<<4)  (layer 2: A cols are permuted)
template<bool PERM>
__global__ void convert_w_kernel(const float* __restrict__ W, uint4* __restrict__ WT, int K) {
    int i = blockIdx.x * blockDim.x + threadIdx.x;
    int ng = K >> 3;
    if (i >= ng * CH) return;
    int g = i >> 7;
    int col = i & 127;
    unsigned int h[8];
    #pragma unroll
    for (int j = 0; j < 8; ++j) {
        int kp = g * 8 + j;
        int k = PERM ? ((kp >> 3) + ((kp & 7) << 4)) : kp;
        h[j] = f2bf(W[(size_t)k * CH + col]);
    }
    uint4 v;
    v.x = h[0] | (h[1] << 16);
    v.y = h[2] | (h[3] << 16);
    v.z = h[4] | (h[5] << 16);
    v.w = h[6] | (h[7] << 16);
    WT[i] = v;
}

// ---------------- GEMM1: g1[M][128](bf16, permuted cols) = (x[M][512] @ W1) * dinv[row] ----------------
// Occupancy-first: 16-row waves (acc=32 VGPR), 1-deep A prefetch, B loaded per k-step
// (WT is L1/L2-hot; its latency is hidden by TLP, not registers).
// __launch_bounds__(256,4) caps VGPR at 128 -> 4-5 waves/SIMD (grid provides ~6/SIMD).
// storage col' = l15*8 + n  (true col = n*16 + l15)
__launch_bounds__(256, 4)
__global__ void gemm1_mfma_kernel(const float* __restrict__ A, const uint4* __restrict__ WT,
                                  const float* __restrict__ dinv, unsigned short* __restrict__ C,
                                  int M) {
    const int tid = threadIdx.x;
    const int wid = tid >> 6;
    const int lane = tid & 63;
    const int l15 = lane & 15;
    const int lg = lane >> 4;

    const int wave_row = blockIdx.x * 64 + wid * 16;   // 16 rows per wave
    const int arow = min(wave_row + l15, M - 1);
    const float4* ap = reinterpret_cast<const float4*>(A + (size_t)arow * IN_CH_K) + lg * 2;
    const uint4* wp = WT + (size_t)lg * CH + l15;   // +4*CH per k-step; +16*n per frag

    f32x4 acc[8];
    #pragma unroll
    for (int n = 0; n < 8; ++n) acc[n] = (f32x4){0.f, 0.f, 0.f, 0.f};

    // ---- prologue: A for k-step 0 ----
    float4 a0 = ap[0], a1 = ap[1];

    #pragma unroll
    for (int ks = 0; ks < 16; ++ks) {
        // 1-deep A prefetch (HBM latency hidden under this step's B-load + cvt + MFMA)
        float4 na0, na1;
        if (ks < 15) {
            na0 = ap[(ks + 1) * 8];
            na1 = ap[(ks + 1) * 8 + 1];
        }

        // B fragments for this k-step (L1/L2-resident)
        const uint4* wpk = wp + (size_t)ks * 4 * CH;
        uint4 bw[8];
        #pragma unroll
        for (int n = 0; n < 8; ++n) bw[n] = wpk[n * 16];

        // convert current A to bf16 fragment
        uint4 pk;
        pk.x = pk2bf(a0.x, a0.y);
        pk.y = pk2bf(a0.z, a0.w);
        pk.z = pk2bf(a1.x, a1.y);
        pk.w = pk2bf(a1.z, a1.w);
        s16x8 af = __builtin_bit_cast(s16x8, pk);

        #pragma unroll
        for (int n = 0; n < 8; ++n) {
            s16x8 b = __builtin_bit_cast(s16x8, bw[n]);
            acc[n] = __builtin_amdgcn_mfma_f32_16x16x32_bf16(af, b, acc[n], 0, 0, 0);
        }

        if (ks < 15) { a0 = na0; a1 = na1; }
    }

    // ---- epilogue: D[row=lg*4+i][col=l15] per frag; scale by dinv[row]; permuted bf16 store ----
    #pragma unroll
    for (int i = 0; i < 4; ++i) {
        int row = wave_row + lg * 4 + i;
        if (row < M) {
            float s = dinv[row];
            uint4 v;
            v.x = pk2bf(acc[0][i] * s, acc[1][i] * s);
            v.y = pk2bf(acc[2][i] * s, acc[3][i] * s);
            v.z = pk2bf(acc[4][i] * s, acc[5][i] * s);
            v.w = pk2bf(acc[6][i] * s, acc[7][i] * s);
            *reinterpret_cast<uint4*>(&C[(size_t)row * CH + l15 * 8]) = v;
        }
    }
}

// ---------------- GEMM2: g2 = (relu(a1)[M][128] @ W2) * dinv[row], all bf16 permuted ----------------
__launch_bounds__(256)
__global__ void gemm2_mfma_kernel(const unsigned short* __restrict__ A, const uint4* __restrict__ WT,
                                  const float* __restrict__ dinv, unsigned short* __restrict__ C,
                                  int M) {
    const int tid = threadIdx.x;
    const int wid = tid >> 6;
    const int lane = tid & 63;
    const int l15 = lane & 15;
    const int lg = lane >> 4;

    const int block_row = blockIdx.x * 128 + wid * 32;

    f32x4 acc[2][8];
    #pragma unroll
    for (int m = 0; m < 2; ++m)
        #pragma unroll
        for (int n = 0; n < 8; ++n)
            acc[m][n] = (f32x4){0.f, 0.f, 0.f, 0.f};

    int arow0 = min(block_row + l15, M - 1);
    int arow1 = min(block_row + 16 + l15, M - 1);
    const uint4* ap0 = reinterpret_cast<const uint4*>(A + (size_t)arow0 * CH);
    const uint4* ap1 = reinterpret_cast<const uint4*>(A + (size_t)arow1 * CH);

    #pragma unroll
    for (int k0 = 0; k0 < CH; k0 += 32) {
        const int fi = (k0 >> 3) + lg;
        uint4 r0 = ap0[fi];
        uint4 r1 = ap1[fi];
        r0.x = relu_pk(r0.x); r0.y = relu_pk(r0.y); r0.z = relu_pk(r0.z); r0.w = relu_pk(r0.w);
        r1.x = relu_pk(r1.x); r1.y = relu_pk(r1.y); r1.z = relu_pk(r1.z); r1.w = relu_pk(r1.w);
        s16x8 a0 = __builtin_bit_cast(s16x8, r0);
        s16x8 a1 = __builtin_bit_cast(s16x8, r1);
        #pragma unroll
        for (int n = 0; n < 8; ++n) {
            uint4 bv = WT[(size_t)fi * CH + n * 16 + l15];
            s16x8 b = __builtin_bit_cast(s16x8, bv);
            acc[0][n] = __builtin_amdgcn_mfma_f32_16x16x32_bf16(a0, b, acc[0][n], 0, 0, 0);
            acc[1][n] = __builtin_amdgcn_mfma_f32_16x16x32_bf16(a1, b, acc[1][n], 0, 0, 0);
        }
    }

    #pragma unroll
    for (int m = 0; m < 2; ++m) {
        #pragma unroll
        for (int i = 0; i < 4; ++i) {
            int row = block_row + m * 16 + lg * 4 + i;
            if (row < M) {
                float s = dinv[row];
                uint4 v;
                v.x = pk2bf(acc[m][0][i] * s, acc[m][1][i] * s);
                v.y = pk2bf(acc[m][2][i] * s, acc[m][3][i] * s);
                v.z = pk2bf(acc[m][4][i] * s, acc[m][5][i] * s);
                v.w = pk2bf(acc[m][6][i] * s, acc[m][7][i] * s);
                *reinterpret_cast<uint4*>(&C[(size_t)row * CH + l15 * 8]) = v;
            }
        }
    }
}

// ---------------- aggregation: out[d] = dinv[d]*(g[d] + sum g[src]) + bias ----------------
// g is bf16 permuted-col [node][128]; one wave per node, 1 uint (2 bf16) per lane.
// 8-deep software-pipelined gather: next batch's indices load while current gathers fly.
#define GATHER(cc) g[(size_t)__builtin_amdgcn_readfirstlane(cc) * 64 + lane]
template<bool OUT_BF16>
__launch_bounds__(256)
__global__ void aggregate_kernel(const unsigned int* __restrict__ g, const int2* __restrict__ row_range,
                                 const int* __restrict__ csr_src, const float* __restrict__ dinv,
                                 const float* __restrict__ bias, void* __restrict__ outp, int N) {
    const int gtid = blockIdx.x * blockDim.x + threadIdx.x;
    const int node = gtid >> 6;
    if (node >= N) return;
    const int lane = threadIdx.x & 63;

    unsigned int su = g[(size_t)node * 64 + lane];   // self-loop term
    const int2 rr = row_range[node];
    float ax = bf_lo(su);
    float ay = bf_hi(su);

    int j = rr.x;
    const int end = rr.y;

    if (j + 8 <= end) {
        int c0 = csr_src[j], c1 = csr_src[j+1], c2 = csr_src[j+2], c3 = csr_src[j+3];
        int c4 = csr_src[j+4], c5 = csr_src[j+5], c6 = csr_src[j+6], c7 = csr_src[j+7];
        j += 8;
        while (j + 8 <= end) {
            int n0 = csr_src[j], n1 = csr_src[j+1], n2 = csr_src[j+2], n3 = csr_src[j+3];
            int n4 = csr_src[j+4], n5 = csr_src[j+5], n6 = csr_src[j+6], n7 = csr_src[j+7];
            j += 8;
            unsigned int u0 = GATHER(c0), u1 = GATHER(c1), u2 = GATHER(c2), u3 = GATHER(c3);
            unsigned int u4 = GATHER(c4), u5 = GATHER(c5), u6 = GATHER(c6), u7 = GATHER(c7);
            ax += ((bf_lo(u0) + bf_lo(u1)) + (bf_lo(u2) + bf_lo(u3)))
                + ((bf_lo(u4) + bf_lo(u5)) + (bf_lo(u6) + bf_lo(u7)));
            ay += ((bf_hi(u0) + bf_hi(u1)) + (bf_hi(u2) + bf_hi(u3)))
                + ((bf_hi(u4) + bf_hi(u5)) + (bf_hi(u6) + bf_hi(u7)));
            c0 = n0; c1 = n1; c2 = n2; c3 = n3;
            c4 = n4; c5 = n5; c6 = n6; c7 = n7;
        }
        unsigned int u0 = GATHER(c0), u1 = GATHER(c1), u2 = GATHER(c2), u3 = GATHER(c3);
        unsigned int u4 = GATHER(c4), u5 = GATHER(c5), u6 = GATHER(c6), u7 = GATHER(c7);
        ax += ((bf_lo(u0) + bf_lo(u1)) + (bf_lo(u2) + bf_lo(u3)))
            + ((bf_lo(u4) + bf_lo(u5)) + (bf_lo(u6) + bf_lo(u7)));
        ay += ((bf_hi(u0) + bf_hi(u1)) + (bf_hi(u2) + bf_hi(u3)))
            + ((bf_hi(u4) + bf_hi(u5)) + (bf_hi(u6) + bf_hi(u7)));
    }
    for (; j + 2 <= end; j += 2) {
        int c0 = csr_src[j], c1 = csr_src[j+1];
        unsigned int u0 = GATHER(c0), u1 = GATHER(c1);
        ax += bf_lo(u0) + bf_lo(u1);
        ay += bf_hi(u0) + bf_hi(u1);
    }
    if (j < end) {
        int c0 = csr_src[j];
        unsigned int u0 = GATHER(c0);
        ax += bf_lo(u0);
        ay += bf_hi(u0);
    }

    const int cp0 = lane << 1;
    const int cp1 = cp0 | 1;
    const int c0 = (cp0 >> 3) + ((cp0 & 7) << 4);    // true cols
    const int c1 = (cp1 >> 3) + ((cp1 & 7) << 4);
    const float di = dinv[node];
    float ox = di * ax + bias[c0];
    float oy = di * ay + bias[c1];
    if (OUT_BF16) {
        ((unsigned int*)outp)[(size_t)node * 64 + lane] = pk2bf(ox, oy);
    } else {
        float* o = (float*)outp + (size_t)node * CH;
        o[c0] = ox;
        o[c1] = oy;
    }
}

extern "C" void kernel_launch(void* const* d_in, const int* in_sizes, int n_in,
                              void* d_out, int out_size, void* d_ws, size_t ws_size,
                              hipStream_t stream) {
    const float* x  = (const float*)d_in[0];
    const int*   ei = (const int*)d_in[1];
    const float* W1 = (const float*)d_in[2];
    const float* b1 = (const float*)d_in[3];
    const float* W2 = (const float*)d_in[4];
    const float* b2 = (const float*)d_in[5];
    float* out = (float*)d_out;

    const int N = in_sizes[0] / IN_CH_K;       // 100000
    const int E = in_sizes[1] / 2;             // 1600000
    const int* e_src = ei;
    const int* e_dst = ei + E;

    const int NB = (N + 255) >> 8;             // 391 coarse buckets
    const int NCHUNK = (E + CHUNK - 1) / CHUNK;

    char* w = (char*)d_ws;
    auto alloc = [&](size_t bytes) {
        char* p = w;
        w += (bytes + 255) & ~(size_t)255;
        return p;
    };
    int*   cursor    = (int*)  alloc((size_t)NB * 4);
    int2*  row_range = (int2*) alloc((size_t)N * 8);
    float* dinv      = (float*)alloc((size_t)N * 4);
    int*   csr_src   = (int*)  alloc((size_t)NB * BPAD * 4);
    uint4* w1t       = (uint4*)alloc((size_t)(IN_CH_K / 8) * CH * 16);
    uint4* w2t       = (uint4*)alloc((size_t)(CH / 8) * CH * 16);
    unsigned short* gbuf = (unsigned short*)alloc((size_t)N * CH * 2);  // g1 / g2
    unsigned short* abuf = (unsigned short*)alloc((size_t)N * CH * 2);  // a1
    int* binned = (int*)gbuf;   // aliases gbuf (8 MB < 25.6 MB): dead before gemm1 writes

    // ---- CSR build (padded bucket sort) + weight conversion ----
    init_cursor_kernel<<<(NB + 255) / 256, 256, 0, stream>>>(cursor, NB);
    bin_kernel<<<NCHUNK, 256, 0, stream>>>(e_src, e_dst, cursor, binned, E, NB);
    csr_bucket_kernel<<<NB, 256, 0, stream>>>(binned, cursor, row_range, csr_src, dinv, N);
    convert_w_kernel<false><<<(IN_CH_K / 8 * CH + 255) / 256, 256, 0, stream>>>(W1, w1t, IN_CH_K);
    convert_w_kernel<true><<<(CH / 8 * CH + 255) / 256, 256, 0, stream>>>(W2, w2t, CH);

    const int gemm1_grid = (N + 63) / 64;      // 64 rows per block (4 waves x 16 rows)
    const int gemm2_grid = (N + 127) / 128;
    const int agg_grid = (N * 64 + 255) / 256;

    // ---- layer 1 ----
    gemm1_mfma_kernel<<<gemm1_grid, 256, 0, stream>>>(x, w1t, dinv, gbuf, N);
    aggregate_kernel<true><<<agg_grid, 256, 0, stream>>>((const unsigned int*)gbuf, row_range,
                                                         csr_src, dinv, b1, abuf, N);

    // ---- layer 2 ----
    gemm2_mfma_kernel<<<gemm2_grid, 256, 0, stream>>>(abuf, w2t, dinv, gbuf, N);
    aggregate_kernel<false><<<agg_grid, 256, 0, stream>>>((const unsigned int*)gbuf, row_range,
                                                          csr_src, dinv, b2, out, N);
}

// Round 10
// 285.216 us; speedup vs baseline: 1.0192x; 1.0056x over previous
//
#include <hip/hip_runtime.h>
#include <hip/hip_bf16.h>

#define CH 128          // HID_CH == OUT_CH == 128
#define IN_CH_K 512
#define CHUNK 2048      // edges per bucket-sort block (782 blocks -> ~3/CU)
#define BPAD 5120       // padded per-bucket capacity (expect ~4096, 16-sigma margin)

typedef short s16x8 __attribute__((ext_vector_type(8)));   // 8 bf16 (4 VGPRs)
typedef float f32x4 __attribute__((ext_vector_type(4)));

__device__ __forceinline__ unsigned int f2bf(float f) {
    unsigned int u = __builtin_bit_cast(unsigned int, f);
    return (u + 0x7fffu + ((u >> 16) & 1u)) >> 16;
}
// packed f32x2 -> bf16x2 via HW cvt (RNE, same bits as f2bf)
__device__ __forceinline__ unsigned int pk2bf(float lo, float hi) {
    unsigned int r;
    asm("v_cvt_pk_bf16_f32 %0, %1, %2" : "=v"(r) : "v"(lo), "v"(hi));
    return r;
}
__device__ __forceinline__ float bf_lo(unsigned int u) {
    return __builtin_bit_cast(float, u << 16);
}
__device__ __forceinline__ float bf_hi(unsigned int u) {
    return __builtin_bit_cast(float, u & 0xFFFF0000u);
}
// relu on 2 packed bf16: zero each 16-bit half whose sign bit is set
__device__ __forceinline__ unsigned int relu_pk(unsigned int w) {
    unsigned int keep = (~w) & 0x80008000u;
    unsigned int mask = keep - (keep >> 15);
    return w & mask;
}

// ---------------- bucket-sort CSR build ----------------
__global__ void init_cursor_kernel(int* __restrict__ cursor, int NB) {
    int i = blockIdx.x * blockDim.x + threadIdx.x;
    if (i < NB) cursor[i] = i * BPAD;
}

// bin edges into padded bucket regions; per-edge cursors in LDS, one global atomic per (block,bucket)
__global__ void bin_kernel(const int* __restrict__ src, const int* __restrict__ dst,
                           int* __restrict__ cursor, int* __restrict__ binned,
                           int E, int NB) {
    __shared__ int h[512];
    __shared__ int base[512];
    __shared__ int cur[512];
    const int tid = threadIdx.x;
    for (int i = tid; i < NB; i += 256) h[i] = 0;
    __syncthreads();

    const int E4 = E >> 2;
    const int beg4 = blockIdx.x * (CHUNK / 4);
    const int end4 = min(E4, beg4 + CHUNK / 4);
    const int4* dst4 = reinterpret_cast<const int4*>(dst);
    const int4* src4 = reinterpret_cast<const int4*>(src);
    const bool last = (blockIdx.x == gridDim.x - 1);

    for (int e4 = beg4 + tid; e4 < end4; e4 += 256) {
        int4 d = dst4[e4];
        atomicAdd(&h[d.x >> 8], 1);
        atomicAdd(&h[d.y >> 8], 1);
        atomicAdd(&h[d.z >> 8], 1);
        atomicAdd(&h[d.w >> 8], 1);
    }
    if (last) {
        for (int e = (E & ~3) + tid; e < E; e += 256)
            atomicAdd(&h[dst[e] >> 8], 1);
    }
    __syncthreads();
    for (int i = tid; i < NB; i += 256) {
        cur[i] = 0;
        if (h[i]) base[i] = atomicAdd(&cursor[i], h[i]);
    }
    __syncthreads();

    for (int e4 = beg4 + tid; e4 < end4; e4 += 256) {
        int4 d = dst4[e4];
        int4 s = src4[e4];
        int b, r, idx;
        b = d.x >> 8; r = atomicAdd(&cur[b], 1); idx = base[b] + r;
        if (idx < (b + 1) * BPAD) binned[idx] = s.x | ((d.x & 255) << 17);
        b = d.y >> 8; r = atomicAdd(&cur[b], 1); idx = base[b] + r;
        if (idx < (b + 1) * BPAD) binned[idx] = s.y | ((d.y & 255) << 17);
        b = d.z >> 8; r = atomicAdd(&cur[b], 1); idx = base[b] + r;
        if (idx < (b + 1) * BPAD) binned[idx] = s.z | ((d.z & 255) << 17);
        b = d.w >> 8; r = atomicAdd(&cur[b], 1); idx = base[b] + r;
        if (idx < (b + 1) * BPAD) binned[idx] = s.w | ((d.w & 255) << 17);
    }
    if (last) {
        for (int e = (E & ~3) + tid; e < E; e += 256) {
            int d = dst[e];
            int b = d >> 8;
            int r = atomicAdd(&cur[b], 1);
            int idx = base[b] + r;
            if (idx < (b + 1) * BPAD) binned[idx] = src[e] | ((d & 255) << 17);
        }
    }
}

// per-bucket (256 nodes) CSR finalize: row ranges, dinv, csr_src; per-edge atomics in LDS
__global__ void csr_bucket_kernel(const int* __restrict__ binned, const int* __restrict__ cursor,
                                  int2* __restrict__ row_range, int* __restrict__ csr_src,
                                  float* __restrict__ dinv, int N) {
    __shared__ int cnt[256];
    __shared__ int off[256];
    __shared__ int cur[256];
    const int k = blockIdx.x;
    const int t = threadIdx.x;
    cnt[t] = 0;
    __syncthreads();
    const int beg = k * BPAD;
    const int end = min(cursor[k], (k + 1) * BPAD);
    const int nv = (end - beg) & ~3;        // vectorizable count (beg is 16B-aligned)
    const int4* b4 = reinterpret_cast<const int4*>(binned + beg);

    for (int q = t; q * 4 < nv; q += 256) {
        int4 p = b4[q];
        atomicAdd(&cnt[p.x >> 17], 1);
        atomicAdd(&cnt[p.y >> 17], 1);
        atomicAdd(&cnt[p.z >> 17], 1);
        atomicAdd(&cnt[p.w >> 17], 1);
    }
    for (int e = beg + nv + t; e < end; e += 256)
        atomicAdd(&cnt[binned[e] >> 17], 1);
    __syncthreads();
    int v = cnt[t];
    off[t] = v;
    __syncthreads();
    #pragma unroll
    for (int o = 1; o < 256; o <<= 1) {
        int tv = (t >= o) ? off[t - o] : 0;
        __syncthreads();
        off[t] += tv;
        __syncthreads();
    }
    int ex = off[t] - v;
    int node = k * 256 + t;
    if (node < N) {
        row_range[node] = make_int2(beg + ex, beg + ex + v);
        dinv[node] = rsqrtf((float)(v + 1));   // +1 self-loop
    }
    cur[t] = ex;
    __syncthreads();
    for (int q = t; q * 4 < nv; q += 256) {
        int4 p = b4[q];
        int dl, r;
        dl = p.x >> 17; r = atomicAdd(&cur[dl], 1); csr_src[beg + r] = p.x & 0x1FFFF;
        dl = p.y >> 17; r = atomicAdd(&cur[dl], 1); csr_src[beg + r] = p.y & 0x1FFFF;
        dl = p.z >> 17; r = atomicAdd(&cur[dl], 1); csr_src[beg + r] = p.z & 0x1FFFF;
        dl = p.w >> 17; r = atomicAdd(&cur[dl], 1); csr_src[beg + r] = p.w & 0x1FFFF;
    }
    for (int e = beg + nv + t; e < end; e += 256) {
        int p = binned[e];
        int dl = p >> 17;
        int r = atomicAdd(&cur[dl], 1);
        csr_src[beg + r] = p & 0x1FFFF;
    }
}

// ---------------- weight pre-transpose to MFMA B-fragment layout ----------------
// WT[g*128 + col] (uint4 = 8 bf16) holds W[k(g*8+j)][col], j=0..7.
// PERM: storage k' -> true k = (k'>>3) + ((k'&7)<<4)  (layer 2: A cols are permuted)
template<bool PERM>
__global__ void convert_w_kernel(const float* __restrict__ W, uint4* __restrict__ WT, int K) {
    int i = blockIdx.x * blockDim.x + threadIdx.x;
    int ng = K >> 3;
    if (i >= ng * CH) return;
    int g = i >> 7;
    int col = i & 127;
    unsigned int h[8];
    #pragma unroll
    for (int j = 0; j < 8; ++j) {
        int kp = g * 8 + j;
        int k = PERM ? ((kp >> 3) + ((kp & 7) << 4)) : kp;
        h[j] = f2bf(W[(size_t)k * CH + col]);
    }
    uint4 v;
    v.x = h[0] | (h[1] << 16);
    v.y = h[2] | (h[3] << 16);
    v.z = h[4] | (h[5] << 16);
    v.w = h[6] | (h[7] << 16);
    WT[i] = v;
}

// ---------------- GEMM1: g1[M][128](bf16, permuted cols) = (x[M][512] @ W1) * dinv[row] ----------------
// LDS-staged streaming: each wave reads one FULL 2KB row per stage iter (64 lanes x 32B,
// perfectly sequential -> max DRAM efficiency), converts to bf16 in-register, ds_write_b128
// into a 64KB XOR-swizzled tile (granule' = granule ^ (row&7); unswizzled would be a 16-way
// bank conflict on the stride-1024B fragment reads). Compute phase reads A-frags via one
// swizzled ds_read_b128 per k-step (2-way conflict = free); B prefetched 1-deep from L2.
// storage col' = l15*8 + n  (true col = n*16 + l15)
__launch_bounds__(256, 2)
__global__ void gemm1_mfma_kernel(const float* __restrict__ A, const uint4* __restrict__ WT,
                                  const float* __restrict__ dinv, unsigned short* __restrict__ C,
                                  int M) {
    __shared__ uint4 As[64 * 64];   // [local row][granule of 8 bf16], swizzled

    const int tid = threadIdx.x;
    const int wid = tid >> 6;
    const int lane = tid & 63;
    const int block_row = blockIdx.x * 64;

    // ---- stage: iter it -> wave wid loads local row it*4+wid contiguously ----
    #pragma unroll
    for (int it = 0; it < 16; ++it) {
        const int lr = it * 4 + wid;
        const int grow = min(block_row + lr, M - 1);
        const float4* srcp = reinterpret_cast<const float4*>(A + (size_t)grow * IN_CH_K) + lane * 2;
        float4 f0 = srcp[0];
        float4 f1 = srcp[1];
        uint4 pk;
        pk.x = pk2bf(f0.x, f0.y);
        pk.y = pk2bf(f0.z, f0.w);
        pk.z = pk2bf(f1.x, f1.y);
        pk.w = pk2bf(f1.z, f1.w);
        As[lr * 64 + (lane ^ (lr & 7))] = pk;
    }
    __syncthreads();

    const int l15 = lane & 15;
    const int lg = lane >> 4;
    const int lr = wid * 16 + l15;                  // local row this lane computes
    const int wave_row = block_row + wid * 16;
    const uint4* wp = WT + (size_t)lg * CH + l15;   // +4*CH per k-step; +16*n per frag

    f32x4 acc[8];
    #pragma unroll
    for (int n = 0; n < 8; ++n) acc[n] = (f32x4){0.f, 0.f, 0.f, 0.f};

    // ---- B prologue (k-step 0) ----
    uint4 bw[8];
    #pragma unroll
    for (int n = 0; n < 8; ++n) bw[n] = wp[n * 16];

    #pragma unroll
    for (int ks = 0; ks < 16; ++ks) {
        // 1-deep B prefetch (L2-resident)
        uint4 nbw[8];
        if (ks < 15) {
            const uint4* nwp = wp + (size_t)(ks + 1) * 4 * CH;
            #pragma unroll
            for (int n = 0; n < 8; ++n) nbw[n] = nwp[n * 16];
        }

        // A fragment from swizzled LDS
        uint4 av = As[lr * 64 + ((ks * 4 + lg) ^ (lr & 7))];
        s16x8 af = __builtin_bit_cast(s16x8, av);

        #pragma unroll
        for (int n = 0; n < 8; ++n) {
            s16x8 b = __builtin_bit_cast(s16x8, bw[n]);
            acc[n] = __builtin_amdgcn_mfma_f32_16x16x32_bf16(af, b, acc[n], 0, 0, 0);
        }

        if (ks < 15) {
            #pragma unroll
            for (int n = 0; n < 8; ++n) bw[n] = nbw[n];
        }
    }

    // ---- epilogue: D[row=lg*4+i][col=l15] per frag; scale by dinv[row]; permuted bf16 store ----
    #pragma unroll
    for (int i = 0; i < 4; ++i) {
        int row = wave_row + lg * 4 + i;
        if (row < M) {
            float s = dinv[row];
            uint4 v;
            v.x = pk2bf(acc[0][i] * s, acc[1][i] * s);
            v.y = pk2bf(acc[2][i] * s, acc[3][i] * s);
            v.z = pk2bf(acc[4][i] * s, acc[5][i] * s);
            v.w = pk2bf(acc[6][i] * s, acc[7][i] * s);
            *reinterpret_cast<uint4*>(&C[(size_t)row * CH + l15 * 8]) = v;
        }
    }
}

// ---------------- GEMM2: g2 = (relu(a1)[M][128] @ W2) * dinv[row], all bf16 permuted ----------------
__launch_bounds__(256)
__global__ void gemm2_mfma_kernel(const unsigned short* __restrict__ A, const uint4* __restrict__ WT,
                                  const float* __restrict__ dinv, unsigned short* __restrict__ C,
                                  int M) {
    const int tid = threadIdx.x;
    const int wid = tid >> 6;
    const int lane = tid & 63;
    const int l15 = lane & 15;
    const int lg = lane >> 4;

    const int block_row = blockIdx.x * 128 + wid * 32;

    f32x4 acc[2][8];
    #pragma unroll
    for (int m = 0; m < 2; ++m)
        #pragma unroll
        for (int n = 0; n < 8; ++n)
            acc[m][n] = (f32x4){0.f, 0.f, 0.f, 0.f};

    int arow0 = min(block_row + l15, M - 1);
    int arow1 = min(block_row + 16 + l15, M - 1);
    const uint4* ap0 = reinterpret_cast<const uint4*>(A + (size_t)arow0 * CH);
    const uint4* ap1 = reinterpret_cast<const uint4*>(A + (size_t)arow1 * CH);

    #pragma unroll
    for (int k0 = 0; k0 < CH; k0 += 32) {
        const int fi = (k0 >> 3) + lg;
        uint4 r0 = ap0[fi];
        uint4 r1 = ap1[fi];
        r0.x = relu_pk(r0.x); r0.y = relu_pk(r0.y); r0.z = relu_pk(r0.z); r0.w = relu_pk(r0.w);
        r1.x = relu_pk(r1.x); r1.y = relu_pk(r1.y); r1.z = relu_pk(r1.z); r1.w = relu_pk(r1.w);
        s16x8 a0 = __builtin_bit_cast(s16x8, r0);
        s16x8 a1 = __builtin_bit_cast(s16x8, r1);
        #pragma unroll
        for (int n = 0; n < 8; ++n) {
            uint4 bv = WT[(size_t)fi * CH + n * 16 + l15];
            s16x8 b = __builtin_bit_cast(s16x8, bv);
            acc[0][n] = __builtin_amdgcn_mfma_f32_16x16x32_bf16(a0, b, acc[0][n], 0, 0, 0);
            acc[1][n] = __builtin_amdgcn_mfma_f32_16x16x32_bf16(a1, b, acc[1][n], 0, 0, 0);
        }
    }

    #pragma unroll
    for (int m = 0; m < 2; ++m) {
        #pragma unroll
        for (int i = 0; i < 4; ++i) {
            int row = block_row + m * 16 + lg * 4 + i;
            if (row < M) {
                float s = dinv[row];
                uint4 v;
                v.x = pk2bf(acc[m][0][i] * s, acc[m][1][i] * s);
                v.y = pk2bf(acc[m][2][i] * s, acc[m][3][i] * s);
                v.z = pk2bf(acc[m][4][i] * s, acc[m][5][i] * s);
                v.w = pk2bf(acc[m][6][i] * s, acc[m][7][i] * s);
                *reinterpret_cast<uint4*>(&C[(size_t)row * CH + l15 * 8]) = v;
            }
        }
    }
}

// ---------------- aggregation: out[d] = dinv[d]*(g[d] + sum g[src]) + bias ----------------
// g is bf16 permuted-col [node][128]; one wave per node, 1 uint (2 bf16) per lane.
// 8-deep software-pipelined gather: next batch's indices load while current gathers fly.
#define GATHER(cc) g[(size_t)__builtin_amdgcn_readfirstlane(cc) * 64 + lane]
template<bool OUT_BF16>
__launch_bounds__(256)
__global__ void aggregate_kernel(const unsigned int* __restrict__ g, const int2* __restrict__ row_range,
                                 const int* __restrict__ csr_src, const float* __restrict__ dinv,
                                 const float* __restrict__ bias, void* __restrict__ outp, int N) {
    const int gtid = blockIdx.x * blockDim.x + threadIdx.x;
    const int node = gtid >> 6;
    if (node >= N) return;
    const int lane = threadIdx.x & 63;

    unsigned int su = g[(size_t)node * 64 + lane];   // self-loop term
    const int2 rr = row_range[node];
    float ax = bf_lo(su);
    float ay = bf_hi(su);

    int j = rr.x;
    const int end = rr.y;

    if (j + 8 <= end) {
        int c0 = csr_src[j], c1 = csr_src[j+1], c2 = csr_src[j+2], c3 = csr_src[j+3];
        int c4 = csr_src[j+4], c5 = csr_src[j+5], c6 = csr_src[j+6], c7 = csr_src[j+7];
        j += 8;
        while (j + 8 <= end) {
            int n0 = csr_src[j], n1 = csr_src[j+1], n2 = csr_src[j+2], n3 = csr_src[j+3];
            int n4 = csr_src[j+4], n5 = csr_src[j+5], n6 = csr_src[j+6], n7 = csr_src[j+7];
            j += 8;
            unsigned int u0 = GATHER(c0), u1 = GATHER(c1), u2 = GATHER(c2), u3 = GATHER(c3);
            unsigned int u4 = GATHER(c4), u5 = GATHER(c5), u6 = GATHER(c6), u7 = GATHER(c7);
            ax += ((bf_lo(u0) + bf_lo(u1)) + (bf_lo(u2) + bf_lo(u3)))
                + ((bf_lo(u4) + bf_lo(u5)) + (bf_lo(u6) + bf_lo(u7)));
            ay += ((bf_hi(u0) + bf_hi(u1)) + (bf_hi(u2) + bf_hi(u3)))
                + ((bf_hi(u4) + bf_hi(u5)) + (bf_hi(u6) + bf_hi(u7)));
            c0 = n0; c1 = n1; c2 = n2; c3 = n3;
            c4 = n4; c5 = n5; c6 = n6; c7 = n7;
        }
        unsigned int u0 = GATHER(c0), u1 = GATHER(c1), u2 = GATHER(c2), u3 = GATHER(c3);
        unsigned int u4 = GATHER(c4), u5 = GATHER(c5), u6 = GATHER(c6), u7 = GATHER(c7);
        ax += ((bf_lo(u0) + bf_lo(u1)) + (bf_lo(u2) + bf_lo(u3)))
            + ((bf_lo(u4) + bf_lo(u5)) + (bf_lo(u6) + bf_lo(u7)));
        ay += ((bf_hi(u0) + bf_hi(u1)) + (bf_hi(u2) + bf_hi(u3)))
            + ((bf_hi(u4) + bf_hi(u5)) + (bf_hi(u6) + bf_hi(u7)));
    }
    for (; j + 2 <= end; j += 2) {
        int c0 = csr_src[j], c1 = csr_src[j+1];
        unsigned int u0 = GATHER(c0), u1 = GATHER(c1);
        ax += bf_lo(u0) + bf_lo(u1);
        ay += bf_hi(u0) + bf_hi(u1);
    }
    if (j < end) {
        int c0 = csr_src[j];
        unsigned int u0 = GATHER(c0);
        ax += bf_lo(u0);
        ay += bf_hi(u0);
    }

    const int cp0 = lane << 1;
    const int cp1 = cp0 | 1;
    const int c0 = (cp0 >> 3) + ((cp0 & 7) << 4);    // true cols
    const int c1 = (cp1 >> 3) + ((cp1 & 7) << 4);
    const float di = dinv[node];
    float ox = di * ax + bias[c0];
    float oy = di * ay + bias[c1];
    if (OUT_BF16) {
        ((unsigned int*)outp)[(size_t)node * 64 + lane] = pk2bf(ox, oy);
    } else {
        float* o = (float*)outp + (size_t)node * CH;
        o[c0] = ox;
        o[c1] = oy;
    }
}

extern "C" void kernel_launch(void* const* d_in, const int* in_sizes, int n_in,
                              void* d_out, int out_size, void* d_ws, size_t ws_size,
                              hipStream_t stream) {
    const float* x  = (const float*)d_in[0];
    const int*   ei = (const int*)d_in[1];
    const float* W1 = (const float*)d_in[2];
    const float* b1 = (const float*)d_in[3];
    const float* W2 = (const float*)d_in[4];
    const float* b2 = (const float*)d_in[5];
    float* out = (float*)d_out;

    const int N = in_sizes[0] / IN_CH_K;       // 100000
    const int E = in_sizes[1] / 2;             // 1600000
    const int* e_src = ei;
    const int* e_dst = ei + E;

    const int NB = (N + 255) >> 8;             // 391 coarse buckets
    const int NCHUNK = (E + CHUNK - 1) / CHUNK;

    char* w = (char*)d_ws;
    auto alloc = [&](size_t bytes) {
        char* p = w;
        w += (bytes + 255) & ~(size_t)255;
        return p;
    };
    int*   cursor    = (int*)  alloc((size_t)NB * 4);
    int2*  row_range = (int2*) alloc((size_t)N * 8);
    float* dinv      = (float*)alloc((size_t)N * 4);
    int*   csr_src   = (int*)  alloc((size_t)NB * BPAD * 4);
    uint4* w1t       = (uint4*)alloc((size_t)(IN_CH_K / 8) * CH * 16);
    uint4* w2t       = (uint4*)alloc((size_t)(CH / 8) * CH * 16);
    unsigned short* gbuf = (unsigned short*)alloc((size_t)N * CH * 2);  // g1 / g2
    unsigned short* abuf = (unsigned short*)alloc((size_t)N * CH * 2);  // a1
    int* binned = (int*)gbuf;   // aliases gbuf (8 MB < 25.6 MB): dead before gemm1 writes

    // ---- CSR build (padded bucket sort) + weight conversion ----
    init_cursor_kernel<<<(NB + 255) / 256, 256, 0, stream>>>(cursor, NB);
    bin_kernel<<<NCHUNK, 256, 0, stream>>>(e_src, e_dst, cursor, binned, E, NB);
    csr_bucket_kernel<<<NB, 256, 0, stream>>>(binned, cursor, row_range, csr_src, dinv, N);
    convert_w_kernel<false><<<(IN_CH_K / 8 * CH + 255) / 256, 256, 0, stream>>>(W1, w1t, IN_CH_K);
    convert_w_kernel<true><<<(CH / 8 * CH + 255) / 256, 256, 0, stream>>>(W2, w2t, CH);

    const int gemm1_grid = (N + 63) / 64;      // 64 rows per block (4 waves x 16 rows)
    const int gemm2_grid = (N + 127) / 128;
    const int agg_grid = (N * 64 + 255) / 256;

    // ---- layer 1 ----
    gemm1_mfma_kernel<<<gemm1_grid, 256, 0, stream>>>(x, w1t, dinv, gbuf, N);
    aggregate_kernel<true><<<agg_grid, 256, 0, stream>>>((const unsigned int*)gbuf, row_range,
                                                         csr_src, dinv, b1, abuf, N);

    // ---- layer 2 ----
    gemm2_mfma_kernel<<<gemm2_grid, 256, 0, stream>>>(abuf, w2t, dinv, gbuf, N);
    aggregate_kernel<false><<<agg_grid, 256, 0, stream>>>((const unsigned int*)gbuf, row_range,
                                                          csr_src, dinv, b2, out, N);
}